// Round 7
// baseline (388.325 us; speedup 1.0000x reference)
//
#include <hip/hip_runtime.h>

// Flash attention fwd: fp32 I/O, bf16 MFMA, fp32 softmax math.
// BH=32, S=2048, D=64, additive mask [2,S,S] tiled bh%2.
// R15: R14 split-K x2 with __launch_bounds__(256, 4). Pattern across R8-R14:
// measured occupancy == declared min-waves-per-EU in ALL six configs
// (2 declared -> 20-22% despite 4 blocks/CU eligible in R11/R14; 4 declared
// -> 43-46% in R9/R10). The launch_bounds 2nd arg empirically acts as the
// residency cap on this stack. Raising it to 4 is safe here: 112 VGPR used
// <= 128 budget at 4 waves/EU (unlike R9/R10's 8/EU -> 64-reg spills).
// Everything else identical to R14 for clean attribution.

constexpr int cBH = 32;
constexpr int cS  = 2048;
constexpr int cD  = 64;
constexpr int cQT = 128;            // 4 waves x 32 q-rows

typedef __bf16 bf16x8 __attribute__((ext_vector_type(8)));
typedef __bf16 bf16x4 __attribute__((ext_vector_type(4)));
typedef float  f32x4  __attribute__((ext_vector_type(4)));
typedef float  f32x16 __attribute__((ext_vector_type(16)));
typedef unsigned int u32x4 __attribute__((ext_vector_type(4)));

__device__ __forceinline__ unsigned short bfbits(float f) {
    return __builtin_bit_cast(unsigned short, (__bf16)f);
}
__device__ __forceinline__ bf16x4 pack4(f32x4 a) {
    bf16x4 r;
    r[0] = (__bf16)a[0]; r[1] = (__bf16)a[1];
    r[2] = (__bf16)a[2]; r[3] = (__bf16)a[3];
    return r;
}
__device__ __forceinline__ bf16x8 pack8s(f32x4 a, f32x4 b, float s) {
    bf16x8 r;
    r[0] = (__bf16)(a[0]*s); r[1] = (__bf16)(a[1]*s);
    r[2] = (__bf16)(a[2]*s); r[3] = (__bf16)(a[3]*s);
    r[4] = (__bf16)(b[0]*s); r[5] = (__bf16)(b[1]*s);
    r[6] = (__bf16)(b[2]*s); r[7] = (__bf16)(b[3]*s);
    return r;
}
__device__ __forceinline__ int gkey(int d) {     // sV swizzle key (d 0..63)
    return (d ^ (d >> 3)) & 7;
}

// ---------------------------------------------------------------------------
// Split-K main kernel: NPAIR pair-iterations starting at k-offset koff.
// Writes RAW (unnormalized) O to opart and row-sums to lpart.
// ---------------------------------------------------------------------------
template <int NPAIR>
__global__ __launch_bounds__(256, 4)
void sdpa_part_kernel(const float* __restrict__ q,
                      const float* __restrict__ k,
                      const float* __restrict__ v,
                      const float* __restrict__ mask,
                      float* __restrict__ out,     // kh==0 raw partial
                      float* __restrict__ wsO,     // kh==1 raw partial
                      float* __restrict__ wsL)     // [2][BH*S] row sums
{
    __shared__ unsigned short sK[2][64 * 64];
    __shared__ unsigned short sV[2][64 * 64];

    const int tid  = threadIdx.x;
    const int wv   = tid >> 6;                          // 0..3
    const int lane = tid & 63;
    const int l31  = lane & 31;
    const int h    = lane >> 5;                         // 32-lane half
    const int swk  = (lane & 7) ^ (((lane >> 3) & 1) << 2);

    const int fid = blockIdx.x;                         // 0..1023
    const int bh  = (fid & 7) | (((fid >> 7) & 3) << 3);
    const int qb  = ((fid >> 3) & 15) * cQT;
    const int kh  = fid >> 9;                           // k-half
    const int mb  = bh & 1;
    const int koff = kh * (NPAIR * 128);                // k-col offset

    const float L2E = 1.4426950408889634f;

    // ---- Q fragments (B-operand), pre-scaled by 0.125*log2(e) ----
    bf16x8 aq[4];
    {
        const float* qp = q + ((size_t)bh * cS + qb + wv * 32 + l31) * cD + h * 8;
#pragma unroll
        for (int dc = 0; dc < 4; ++dc)
            aq[dc] = pack8s(*(const f32x4*)(qp + dc * 16),
                            *(const f32x4*)(qp + dc * 16 + 4), 0.125f * L2E);
    }

    f32x16 acc[2] = {};       // O[q][d]: dg in {0,1} -> d = dg*32 + l31
    float lsum = 0.f;

    // ---- staging geometry ----
    const int sr0 = tid >> 4;                 // 0..15
    const int c4  = (tid & 15) << 2;
    const int ka0 = sr0 * 64
        + ((((c4 >> 3) ^ (sr0 & 7) ^ (((sr0 >> 3) & 1) << 2)) << 3))
        + (c4 & 7);
    const float* kg = k + (size_t)bh * cS * cD + (size_t)koff * cD;
    const float* vg = v + (size_t)bh * cS * cD + (size_t)koff * cD;
    const float* mq = mask + (size_t)mb * cS * cS
                           + (size_t)(qb + wv * 32 + l31) * cS + koff + h * 4;

    const int g0 = gkey(l31);
    const int g1 = gkey(32 + l31);
    const int vb0 = l31 * 64;
    const int vb1 = (32 + l31) * 64;

    // ---- prologue: stage pair 0 ----
#pragma unroll
    for (int t = 0; t < 2; ++t)
#pragma unroll
        for (int j = 0; j < 4; ++j) {
            f32x4 kj = *(const f32x4*)(kg + t * 4096 + j * 1024 + tid * 4);
            f32x4 vj = *(const f32x4*)(vg + t * 4096 + j * 1024 + tid * 4);
            *(bf16x4*)&sK[t][ka0 + j * 1024] = pack4(kj);
#pragma unroll
            for (int i = 0; i < 4; ++i) {
                int d = c4 + i;
                sV[t][d * 64 + ((((j * 2) + (sr0 >> 3)) ^ gkey(d)) << 3) + (sr0 & 7)]
                    = bfbits(vj[i]);
            }
        }

    for (int pt = 0; pt < NPAIR; ++pt) {
        const int base = pt * 2;
        const bool more = (pt + 1 < NPAIR);
        const int nb = more ? base + 2 : base;      // clamped: uncond. loads

        // ---- prefetch next pair K/V into registers ----
        f32x4 KPe[4], VPe[4], KPo[4], VPo[4];
#pragma unroll
        for (int j = 0; j < 4; ++j) {
            KPe[j] = *(const f32x4*)(kg + (size_t)nb * 4096 + j * 1024 + tid * 4);
            VPe[j] = *(const f32x4*)(vg + (size_t)nb * 4096 + j * 1024 + tid * 4);
            KPo[j] = *(const f32x4*)(kg + (size_t)(nb + 1) * 4096 + j * 1024 + tid * 4);
            VPo[j] = *(const f32x4*)(vg + (size_t)(nb + 1) * 4096 + j * 1024 + tid * 4);
        }

        __syncthreads();                            // pair staged & visible

#pragma unroll
        for (int t = 0; t < 2; ++t) {
            const unsigned short* sKt = sK[t];
            const unsigned short* sVt = sV[t];
#pragma unroll
            for (int gg = 0; gg < 2; ++gg) {
                // ---- mask (JIT, R12 scheme) ----
                const float* mrow = mq + (size_t)(base + t) * 64 + gg * 32;
                f32x4 mk[4];
#pragma unroll
                for (int j = 0; j < 4; ++j)
                    mk[j] = *(const f32x4*)(mrow + j * 8);

                // ---- QK^T swapped: S^T[k][q], A = K rows gg*32..+31 ----
                const int rb = (gg * 32 + l31) * 64;
                bf16x8 kf[4];
#pragma unroll
                for (int dc = 0; dc < 4; ++dc)
                    kf[dc] = *(const bf16x8*)(&sKt[rb + (((dc * 2 + h) ^ swk) << 3)]);
                f32x16 s = {};
#pragma unroll
                for (int dc = 0; dc < 4; ++dc)
                    s = __builtin_amdgcn_mfma_f32_32x32x16_bf16(kf[dc], aq[dc], s, 0, 0, 0);

                // ---- exp2(S + mask*log2e) ----
                float p[16];
#pragma unroll
                for (int r = 0; r < 16; ++r)
                    p[r] = __builtin_amdgcn_exp2f(fmaf(mk[r >> 2][r & 3], L2E, s[r]));
#pragma unroll
                for (int r = 0; r < 16; ++r)
                    lsum += p[r];

                // ---- pack to bf16 pairs; permlane32_swap builds A-frags ----
                unsigned int pk[8];
#pragma unroll
                for (int i = 0; i < 8; ++i)
                    pk[i] = (unsigned int)bfbits(p[2 * i])
                          | ((unsigned int)bfbits(p[2 * i + 1]) << 16);
                asm("v_permlane32_swap_b32 %0, %1" : "+v"(pk[0]), "+v"(pk[2]));
                asm("v_permlane32_swap_b32 %0, %1" : "+v"(pk[1]), "+v"(pk[3]));
                asm("v_permlane32_swap_b32 %0, %1" : "+v"(pk[4]), "+v"(pk[6]));
                asm("v_permlane32_swap_b32 %0, %1" : "+v"(pk[5]), "+v"(pk[7]));
                u32x4 ua = {pk[0], pk[1], pk[2], pk[3]};
                u32x4 ub = {pk[4], pk[5], pk[6], pk[7]};
                bf16x8 fA0 = __builtin_bit_cast(bf16x8, ua);   // k = gg*32 + 0..15
                bf16x8 fA1 = __builtin_bit_cast(bf16x8, ub);   // k = gg*32 + 16..31

                // ---- PV: O[q][d] += P V ----
#pragma unroll
                for (int kc = 0; kc < 2; ++kc) {
                    const int kb = gg * 4 + kc * 2 + h;
                    bf16x8 bv0 = *(const bf16x8*)(&sVt[vb0 + ((kb ^ g0) << 3)]);
                    bf16x8 bv1 = *(const bf16x8*)(&sVt[vb1 + ((kb ^ g1) << 3)]);
                    acc[0] = __builtin_amdgcn_mfma_f32_32x32x16_bf16(
                        kc ? fA1 : fA0, bv0, acc[0], 0, 0, 0);
                    acc[1] = __builtin_amdgcn_mfma_f32_32x32x16_bf16(
                        kc ? fA1 : fA0, bv1, acc[1], 0, 0, 0);
                }
            }
        }

        __syncthreads();                            // pair reads complete

        // ---- stage next pair from registers ----
        if (more) {
#pragma unroll
            for (int j = 0; j < 4; ++j) {
                *(bf16x4*)&sK[0][ka0 + j * 1024] = pack4(KPe[j]);
                *(bf16x4*)&sK[1][ka0 + j * 1024] = pack4(KPo[j]);
#pragma unroll
                for (int i = 0; i < 4; ++i) {
                    int d = c4 + i;
                    int va = d * 64 + ((((j * 2) + (sr0 >> 3)) ^ gkey(d)) << 3) + (sr0 & 7);
                    sV[0][va] = bfbits(VPe[j][i]);
                    sV[1][va] = bfbits(VPo[j][i]);
                }
            }
        }
    }

    // ---- epilogue: RAW partial store (no normalize) ----
    lsum += __shfl_xor(lsum, 32, 64);
    float* opart = kh ? wsO : out;
#pragma unroll
    for (int r = 0; r < 16; ++r) {
        const int qrow = (r & 3) + 8 * (r >> 2) + 4 * h;
        float* op = opart + ((size_t)bh * cS + qb + wv * 32 + qrow) * cD + l31;
        op[0]  = acc[0][r];
        op[32] = acc[1][r];
    }
    if (h == 0)
        wsL[(size_t)kh * (cBH * cS) + (size_t)bh * cS + qb + wv * 32 + l31] = lsum;
}

// ---------------------------------------------------------------------------
// Merge: out = (O0 + O1) / (l0 + l1).  8 floats / thread.
// ---------------------------------------------------------------------------
__global__ __launch_bounds__(256)
void sdpa_merge_kernel(float* __restrict__ out,
                       const float* __restrict__ wsO,
                       const float* __restrict__ wsL)
{
    const size_t gid = (size_t)blockIdx.x * 256 + threadIdx.x;   // 0..524287
    const size_t e0  = gid * 8;
    const size_t row = e0 >> 6;                                  // 0..65535
    const float rl = 1.0f / (wsL[row] + wsL[(size_t)cBH * cS + row]);
    f32x4 a0 = *(const f32x4*)(out + e0);
    f32x4 a1 = *(const f32x4*)(out + e0 + 4);
    f32x4 b0 = *(const f32x4*)(wsO + e0);
    f32x4 b1 = *(const f32x4*)(wsO + e0 + 4);
#pragma unroll
    for (int i = 0; i < 4; ++i) {
        a0[i] = (a0[i] + b0[i]) * rl;
        a1[i] = (a1[i] + b1[i]) * rl;
    }
    *(f32x4*)(out + e0)     = a0;
    *(f32x4*)(out + e0 + 4) = a1;
}

// ---------------------------------------------------------------------------
// Fallback: R12 single-pass (grid 512), used only if workspace too small.
// ---------------------------------------------------------------------------
__global__ __launch_bounds__(256, 2)
void sdpa_flash_kernel(const float* __restrict__ q,
                       const float* __restrict__ k,
                       const float* __restrict__ v,
                       const float* __restrict__ mask,
                       float* __restrict__ out)
{
    __shared__ unsigned short sK[2][64 * 64];
    __shared__ unsigned short sV[2][64 * 64];

    const int tid  = threadIdx.x;
    const int wv   = tid >> 6;
    const int lane = tid & 63;
    const int l31  = lane & 31;
    const int h    = lane >> 5;
    const int swk  = (lane & 7) ^ (((lane >> 3) & 1) << 2);

    const int fid = blockIdx.x;
    const int bh  = (fid & 7) | ((fid >> 7) << 3);
    const int qb  = ((fid >> 3) & 15) * cQT;
    const int mb  = bh & 1;

    const float L2E = 1.4426950408889634f;

    bf16x8 aq[4];
    {
        const float* qp = q + ((size_t)bh * cS + qb + wv * 32 + l31) * cD + h * 8;
#pragma unroll
        for (int dc = 0; dc < 4; ++dc)
            aq[dc] = pack8s(*(const f32x4*)(qp + dc * 16),
                            *(const f32x4*)(qp + dc * 16 + 4), 0.125f * L2E);
    }

    f32x16 acc[2] = {};
    float lsum = 0.f;

    const int sr0 = tid >> 4;
    const int c4  = (tid & 15) << 2;
    const int ka0 = sr0 * 64
        + ((((c4 >> 3) ^ (sr0 & 7) ^ (((sr0 >> 3) & 1) << 2)) << 3))
        + (c4 & 7);
    const float* kg = k + (size_t)bh * cS * cD;
    const float* vg = v + (size_t)bh * cS * cD;
    const float* mq = mask + (size_t)mb * cS * cS
                           + (size_t)(qb + wv * 32 + l31) * cS + h * 4;

    const int g0 = gkey(l31);
    const int g1 = gkey(32 + l31);
    const int vb0 = l31 * 64;
    const int vb1 = (32 + l31) * 64;

#pragma unroll
    for (int t = 0; t < 2; ++t)
#pragma unroll
        for (int j = 0; j < 4; ++j) {
            f32x4 kj = *(const f32x4*)(kg + t * 4096 + j * 1024 + tid * 4);
            f32x4 vj = *(const f32x4*)(vg + t * 4096 + j * 1024 + tid * 4);
            *(bf16x4*)&sK[t][ka0 + j * 1024] = pack4(kj);
#pragma unroll
            for (int i = 0; i < 4; ++i) {
                int d = c4 + i;
                sV[t][d * 64 + ((((j * 2) + (sr0 >> 3)) ^ gkey(d)) << 3) + (sr0 & 7)]
                    = bfbits(vj[i]);
            }
        }

    for (int pt = 0; pt < 16; ++pt) {
        const int base = pt * 2;
        const bool more = (pt + 1 < 16);
        const int nb = more ? base + 2 : base;

        f32x4 KPe[4], VPe[4], KPo[4], VPo[4];
#pragma unroll
        for (int j = 0; j < 4; ++j) {
            KPe[j] = *(const f32x4*)(kg + (size_t)nb * 4096 + j * 1024 + tid * 4);
            VPe[j] = *(const f32x4*)(vg + (size_t)nb * 4096 + j * 1024 + tid * 4);
            KPo[j] = *(const f32x4*)(kg + (size_t)(nb + 1) * 4096 + j * 1024 + tid * 4);
            VPo[j] = *(const f32x4*)(vg + (size_t)(nb + 1) * 4096 + j * 1024 + tid * 4);
        }

        __syncthreads();

#pragma unroll
        for (int t = 0; t < 2; ++t) {
            const unsigned short* sKt = sK[t];
            const unsigned short* sVt = sV[t];
#pragma unroll
            for (int gg = 0; gg < 2; ++gg) {
                const float* mrow = mq + (size_t)(base + t) * 64 + gg * 32;
                f32x4 mk[4];
#pragma unroll
                for (int j = 0; j < 4; ++j)
                    mk[j] = *(const f32x4*)(mrow + j * 8);

                const int rb = (gg * 32 + l31) * 64;
                bf16x8 kf[4];
#pragma unroll
                for (int dc = 0; dc < 4; ++dc)
                    kf[dc] = *(const bf16x8*)(&sKt[rb + (((dc * 2 + h) ^ swk) << 3)]);
                f32x16 s = {};
#pragma unroll
                for (int dc = 0; dc < 4; ++dc)
                    s = __builtin_amdgcn_mfma_f32_32x32x16_bf16(kf[dc], aq[dc], s, 0, 0, 0);

                float p[16];
#pragma unroll
                for (int r = 0; r < 16; ++r)
                    p[r] = __builtin_amdgcn_exp2f(fmaf(mk[r >> 2][r & 3], L2E, s[r]));
#pragma unroll
                for (int r = 0; r < 16; ++r)
                    lsum += p[r];

                unsigned int pk[8];
#pragma unroll
                for (int i = 0; i < 8; ++i)
                    pk[i] = (unsigned int)bfbits(p[2 * i])
                          | ((unsigned int)bfbits(p[2 * i + 1]) << 16);
                asm("v_permlane32_swap_b32 %0, %1" : "+v"(pk[0]), "+v"(pk[2]));
                asm("v_permlane32_swap_b32 %0, %1" : "+v"(pk[1]), "+v"(pk[3]));
                asm("v_permlane32_swap_b32 %0, %1" : "+v"(pk[4]), "+v"(pk[6]));
                asm("v_permlane32_swap_b32 %0, %1" : "+v"(pk[5]), "+v"(pk[7]));
                u32x4 ua = {pk[0], pk[1], pk[2], pk[3]};
                u32x4 ub = {pk[4], pk[5], pk[6], pk[7]};
                bf16x8 fA0 = __builtin_bit_cast(bf16x8, ua);
                bf16x8 fA1 = __builtin_bit_cast(bf16x8, ub);

#pragma unroll
                for (int kc = 0; kc < 2; ++kc) {
                    const int kb = gg * 4 + kc * 2 + h;
                    bf16x8 bv0 = *(const bf16x8*)(&sVt[vb0 + ((kb ^ g0) << 3)]);
                    bf16x8 bv1 = *(const bf16x8*)(&sVt[vb1 + ((kb ^ g1) << 3)]);
                    acc[0] = __builtin_amdgcn_mfma_f32_32x32x16_bf16(
                        kc ? fA1 : fA0, bv0, acc[0], 0, 0, 0);
                    acc[1] = __builtin_amdgcn_mfma_f32_32x32x16_bf16(
                        kc ? fA1 : fA0, bv1, acc[1], 0, 0, 0);
                }
            }
        }

        __syncthreads();

        if (more) {
#pragma unroll
            for (int j = 0; j < 4; ++j) {
                *(bf16x4*)&sK[0][ka0 + j * 1024] = pack4(KPe[j]);
                *(bf16x4*)&sK[1][ka0 + j * 1024] = pack4(KPo[j]);
#pragma unroll
                for (int i = 0; i < 4; ++i) {
                    int d = c4 + i;
                    int va = d * 64 + ((((j * 2) + (sr0 >> 3)) ^ gkey(d)) << 3) + (sr0 & 7);
                    sV[0][va] = bfbits(VPe[j][i]);
                    sV[1][va] = bfbits(VPo[j][i]);
                }
            }
        }
    }

    lsum += __shfl_xor(lsum, 32, 64);
#pragma unroll
    for (int r = 0; r < 16; ++r) {
        const int qrow = (r & 3) + 8 * (r >> 2) + 4 * h;
        const float rl = 1.0f / __shfl(lsum, qrow, 64);
        float* op = out + ((size_t)bh * cS + qb + wv * 32 + qrow) * cD + l31;
        op[0]  = acc[0][r] * rl;
        op[32] = acc[1][r] * rl;
    }
}

extern "C" void kernel_launch(void* const* d_in, const int* in_sizes, int n_in,
                              void* d_out, int out_size, void* d_ws, size_t ws_size,
                              hipStream_t stream) {
    const float* q = (const float*)d_in[0];
    const float* k = (const float*)d_in[1];
    const float* v = (const float*)d_in[2];
    const float* m = (const float*)d_in[3];
    float* o = (float*)d_out;

    // workspace: wsL [2][BH*S] floats, then wsO [BH*S*D] floats
    const size_t nL   = (size_t)2 * cBH * cS;                 // 131072 floats
    const size_t nO   = (size_t)cBH * cS * cD;                // 4194304 floats
    const size_t need = (nL + nO) * sizeof(float);            // ~16.5 MB

    if (d_ws != nullptr && ws_size >= need) {
        float* wsL = (float*)d_ws;
        float* wsO = wsL + nL;
        sdpa_part_kernel<8><<<dim3(1024), 256, 0, stream>>>(q, k, v, m, o, wsO, wsL);
        sdpa_merge_kernel<<<dim3((unsigned)(nO / 8 / 256)), 256, 0, stream>>>(o, wsO, wsL);
    } else {
        sdpa_flash_kernel<<<dim3(512), 256, 0, stream>>>(q, k, v, m, o);
    }
}

// Round 8
// 201.061 us; speedup vs baseline: 1.9314x; 1.9314x over previous
//
#include <hip/hip_runtime.h>

// Flash attention fwd: fp32 I/O, bf16 MFMA, fp32 softmax math.
// BH=32, S=2048, D=64, additive mask [2,S,S] tiled bh%2.
// R16: split-K x2 with 512-thread blocks and __launch_bounds__(512, 1).
// Ledger: launch_bounds 2nd arg sets the reg budget (2 -> 128 clean;
// 4 -> 64 + spills, three reproductions R9/R10/R15). m214 proves 512-thr
// blocks can hold 205-249 VGPR with min=1. Here: 8 waves x 32 q-rows
// (QT=256), grid 512 = 32 bh x 8 qt x 2 kh, LDS 32 KB, per-thread staging
// halves (prefetch regs 64 -> 32). If VGPR <= 128, HW co-resides 2
// blocks/CU = 4 waves/SIMD -- occupancy via hardware arithmetic, not a
// declared min. Inner math identical to R14 (verified absmax 0.002).

constexpr int cBH = 32;
constexpr int cS  = 2048;
constexpr int cD  = 64;

typedef __bf16 bf16x8 __attribute__((ext_vector_type(8)));
typedef __bf16 bf16x4 __attribute__((ext_vector_type(4)));
typedef float  f32x4  __attribute__((ext_vector_type(4)));
typedef float  f32x16 __attribute__((ext_vector_type(16)));
typedef unsigned int u32x4 __attribute__((ext_vector_type(4)));

__device__ __forceinline__ unsigned short bfbits(float f) {
    return __builtin_bit_cast(unsigned short, (__bf16)f);
}
__device__ __forceinline__ bf16x4 pack4(f32x4 a) {
    bf16x4 r;
    r[0] = (__bf16)a[0]; r[1] = (__bf16)a[1];
    r[2] = (__bf16)a[2]; r[3] = (__bf16)a[3];
    return r;
}
__device__ __forceinline__ bf16x8 pack8s(f32x4 a, f32x4 b, float s) {
    bf16x8 r;
    r[0] = (__bf16)(a[0]*s); r[1] = (__bf16)(a[1]*s);
    r[2] = (__bf16)(a[2]*s); r[3] = (__bf16)(a[3]*s);
    r[4] = (__bf16)(b[0]*s); r[5] = (__bf16)(b[1]*s);
    r[6] = (__bf16)(b[2]*s); r[7] = (__bf16)(b[3]*s);
    return r;
}
__device__ __forceinline__ int gkey(int d) {     // sV swizzle key (d 0..63)
    return (d ^ (d >> 3)) & 7;
}

// ---------------------------------------------------------------------------
// Split-K main kernel, 512 threads: 8 waves x 32 q-rows (QT=256).
// NPAIR pair-iterations starting at k-offset kh*NPAIR*128.
// Writes RAW (unnormalized) O partial and row-sums.
// ---------------------------------------------------------------------------
template <int NPAIR>
__global__ __launch_bounds__(512, 1)
void sdpa_part_kernel(const float* __restrict__ q,
                      const float* __restrict__ k,
                      const float* __restrict__ v,
                      const float* __restrict__ mask,
                      float* __restrict__ out,     // kh==0 raw partial
                      float* __restrict__ wsO,     // kh==1 raw partial
                      float* __restrict__ wsL)     // [2][BH*S] row sums
{
    __shared__ unsigned short sK[2][64 * 64];
    __shared__ unsigned short sV[2][64 * 64];

    const int tid  = threadIdx.x;
    const int wv   = tid >> 6;                          // 0..7
    const int lane = tid & 63;
    const int l31  = lane & 31;
    const int h    = lane >> 5;                         // 32-lane half
    const int swk  = (lane & 7) ^ (((lane >> 3) & 1) << 2);

    const int fid = blockIdx.x;                         // 0..511
    const int bh  = (fid & 7) | (((fid >> 6) & 3) << 3);
    const int qt  = (fid >> 3) & 7;
    const int kh  = fid >> 8;                           // k-half
    const int qb  = qt * 256;
    const int mb  = bh & 1;
    const int koff = kh * (NPAIR * 128);                // k-col offset

    const float L2E = 1.4426950408889634f;

    // ---- Q fragments (B-operand), pre-scaled by 0.125*log2(e) ----
    bf16x8 aq[4];
    {
        const float* qp = q + ((size_t)bh * cS + qb + wv * 32 + l31) * cD + h * 8;
#pragma unroll
        for (int dc = 0; dc < 4; ++dc)
            aq[dc] = pack8s(*(const f32x4*)(qp + dc * 16),
                            *(const f32x4*)(qp + dc * 16 + 4), 0.125f * L2E);
    }

    f32x16 acc[2] = {};       // O[q][d]: dg in {0,1} -> d = dg*32 + l31
    float lsum = 0.f;

    // ---- staging geometry: 512 threads; chunk j = floats j*2048 + tid*4 ----
    const int sr0 = tid >> 4;                 // 0..31
    const int c4  = (tid & 15) << 2;
    const int ka0 = sr0 * 64
        + ((((c4 >> 3) ^ (sr0 & 7) ^ (((sr0 >> 3) & 1) << 2)) << 3))
        + (c4 & 7);
    const float* kg = k + (size_t)bh * cS * cD + (size_t)koff * cD;
    const float* vg = v + (size_t)bh * cS * cD + (size_t)koff * cD;
    const float* mq = mask + (size_t)mb * cS * cS
                           + (size_t)(qb + wv * 32 + l31) * cS + koff + h * 4;

    const int g0 = gkey(l31);
    const int g1 = gkey(32 + l31);
    const int vb0 = l31 * 64;
    const int vb1 = (32 + l31) * 64;

    // ---- prologue: stage pair 0 ----
#pragma unroll
    for (int t = 0; t < 2; ++t)
#pragma unroll
        for (int j = 0; j < 2; ++j) {
            f32x4 kj = *(const f32x4*)(kg + t * 4096 + j * 2048 + tid * 4);
            f32x4 vj = *(const f32x4*)(vg + t * 4096 + j * 2048 + tid * 4);
            *(bf16x4*)&sK[t][ka0 + j * 2048] = pack4(kj);
#pragma unroll
            for (int i = 0; i < 4; ++i) {
                int d = c4 + i;
                sV[t][d * 64 + ((((j * 4) + (sr0 >> 3)) ^ gkey(d)) << 3) + (sr0 & 7)]
                    = bfbits(vj[i]);
            }
        }

    for (int pt = 0; pt < NPAIR; ++pt) {
        const int base = pt * 2;
        const bool more = (pt + 1 < NPAIR);
        const int nb = more ? base + 2 : base;      // clamped: uncond. loads

        // ---- prefetch next pair K/V into registers (32 VGPRs) ----
        f32x4 KPe[2], VPe[2], KPo[2], VPo[2];
#pragma unroll
        for (int j = 0; j < 2; ++j) {
            KPe[j] = *(const f32x4*)(kg + (size_t)nb * 4096 + j * 2048 + tid * 4);
            VPe[j] = *(const f32x4*)(vg + (size_t)nb * 4096 + j * 2048 + tid * 4);
            KPo[j] = *(const f32x4*)(kg + (size_t)(nb + 1) * 4096 + j * 2048 + tid * 4);
            VPo[j] = *(const f32x4*)(vg + (size_t)(nb + 1) * 4096 + j * 2048 + tid * 4);
        }

        __syncthreads();                            // pair staged & visible

#pragma unroll
        for (int t = 0; t < 2; ++t) {
            const unsigned short* sKt = sK[t];
            const unsigned short* sVt = sV[t];
#pragma unroll
            for (int gg = 0; gg < 2; ++gg) {
                // ---- mask (JIT, R12 scheme) ----
                const float* mrow = mq + (size_t)(base + t) * 64 + gg * 32;
                f32x4 mk[4];
#pragma unroll
                for (int j = 0; j < 4; ++j)
                    mk[j] = *(const f32x4*)(mrow + j * 8);

                // ---- QK^T swapped: S^T[k][q], A = K rows gg*32..+31 ----
                const int rb = (gg * 32 + l31) * 64;
                bf16x8 kf[4];
#pragma unroll
                for (int dc = 0; dc < 4; ++dc)
                    kf[dc] = *(const bf16x8*)(&sKt[rb + (((dc * 2 + h) ^ swk) << 3)]);
                f32x16 s = {};
#pragma unroll
                for (int dc = 0; dc < 4; ++dc)
                    s = __builtin_amdgcn_mfma_f32_32x32x16_bf16(kf[dc], aq[dc], s, 0, 0, 0);

                // ---- exp2(S + mask*log2e) ----
                float p[16];
#pragma unroll
                for (int r = 0; r < 16; ++r)
                    p[r] = __builtin_amdgcn_exp2f(fmaf(mk[r >> 2][r & 3], L2E, s[r]));
#pragma unroll
                for (int r = 0; r < 16; ++r)
                    lsum += p[r];

                // ---- pack to bf16 pairs; permlane32_swap builds A-frags ----
                unsigned int pk[8];
#pragma unroll
                for (int i = 0; i < 8; ++i)
                    pk[i] = (unsigned int)bfbits(p[2 * i])
                          | ((unsigned int)bfbits(p[2 * i + 1]) << 16);
                asm("v_permlane32_swap_b32 %0, %1" : "+v"(pk[0]), "+v"(pk[2]));
                asm("v_permlane32_swap_b32 %0, %1" : "+v"(pk[1]), "+v"(pk[3]));
                asm("v_permlane32_swap_b32 %0, %1" : "+v"(pk[4]), "+v"(pk[6]));
                asm("v_permlane32_swap_b32 %0, %1" : "+v"(pk[5]), "+v"(pk[7]));
                u32x4 ua = {pk[0], pk[1], pk[2], pk[3]};
                u32x4 ub = {pk[4], pk[5], pk[6], pk[7]};
                bf16x8 fA0 = __builtin_bit_cast(bf16x8, ua);   // k = gg*32 + 0..15
                bf16x8 fA1 = __builtin_bit_cast(bf16x8, ub);   // k = gg*32 + 16..31

                // ---- PV: O[q][d] += P V ----
#pragma unroll
                for (int kc = 0; kc < 2; ++kc) {
                    const int kb = gg * 4 + kc * 2 + h;
                    bf16x8 bv0 = *(const bf16x8*)(&sVt[vb0 + ((kb ^ g0) << 3)]);
                    bf16x8 bv1 = *(const bf16x8*)(&sVt[vb1 + ((kb ^ g1) << 3)]);
                    acc[0] = __builtin_amdgcn_mfma_f32_32x32x16_bf16(
                        kc ? fA1 : fA0, bv0, acc[0], 0, 0, 0);
                    acc[1] = __builtin_amdgcn_mfma_f32_32x32x16_bf16(
                        kc ? fA1 : fA0, bv1, acc[1], 0, 0, 0);
                }
            }
        }

        __syncthreads();                            // pair reads complete

        // ---- stage next pair from registers ----
        if (more) {
#pragma unroll
            for (int j = 0; j < 2; ++j) {
                *(bf16x4*)&sK[0][ka0 + j * 2048] = pack4(KPe[j]);
                *(bf16x4*)&sK[1][ka0 + j * 2048] = pack4(KPo[j]);
#pragma unroll
                for (int i = 0; i < 4; ++i) {
                    int d = c4 + i;
                    int va = d * 64 + ((((j * 4) + (sr0 >> 3)) ^ gkey(d)) << 3) + (sr0 & 7);
                    sV[0][va] = bfbits(VPe[j][i]);
                    sV[1][va] = bfbits(VPo[j][i]);
                }
            }
        }
    }

    // ---- epilogue: RAW partial store (no normalize) ----
    lsum += __shfl_xor(lsum, 32, 64);
    float* opart = kh ? wsO : out;
#pragma unroll
    for (int r = 0; r < 16; ++r) {
        const int qrow = (r & 3) + 8 * (r >> 2) + 4 * h;
        float* op = opart + ((size_t)bh * cS + qb + wv * 32 + qrow) * cD + l31;
        op[0]  = acc[0][r];
        op[32] = acc[1][r];
    }
    if (h == 0)
        wsL[(size_t)kh * (cBH * cS) + (size_t)bh * cS + qb + wv * 32 + l31] = lsum;
}

// ---------------------------------------------------------------------------
// Merge: out = (O0 + O1) / (l0 + l1).  8 floats / thread.
// ---------------------------------------------------------------------------
__global__ __launch_bounds__(256)
void sdpa_merge_kernel(float* __restrict__ out,
                       const float* __restrict__ wsO,
                       const float* __restrict__ wsL)
{
    const size_t gid = (size_t)blockIdx.x * 256 + threadIdx.x;   // 0..524287
    const size_t e0  = gid * 8;
    const size_t row = e0 >> 6;                                  // 0..65535
    const float rl = 1.0f / (wsL[row] + wsL[(size_t)cBH * cS + row]);
    f32x4 a0 = *(const f32x4*)(out + e0);
    f32x4 a1 = *(const f32x4*)(out + e0 + 4);
    f32x4 b0 = *(const f32x4*)(wsO + e0);
    f32x4 b1 = *(const f32x4*)(wsO + e0 + 4);
#pragma unroll
    for (int i = 0; i < 4; ++i) {
        a0[i] = (a0[i] + b0[i]) * rl;
        a1[i] = (a1[i] + b1[i]) * rl;
    }
    *(f32x4*)(out + e0)     = a0;
    *(f32x4*)(out + e0 + 4) = a1;
}

// ---------------------------------------------------------------------------
// Fallback: R12 single-pass (grid 512, 256 thr), if workspace too small.
// ---------------------------------------------------------------------------
__global__ __launch_bounds__(256, 2)
void sdpa_flash_kernel(const float* __restrict__ q,
                       const float* __restrict__ k,
                       const float* __restrict__ v,
                       const float* __restrict__ mask,
                       float* __restrict__ out)
{
    __shared__ unsigned short sK[2][64 * 64];
    __shared__ unsigned short sV[2][64 * 64];

    const int tid  = threadIdx.x;
    const int wv   = tid >> 6;
    const int lane = tid & 63;
    const int l31  = lane & 31;
    const int h    = lane >> 5;
    const int swk  = (lane & 7) ^ (((lane >> 3) & 1) << 2);

    const int fid = blockIdx.x;
    const int bh  = (fid & 7) | ((fid >> 7) << 3);
    const int qb  = ((fid >> 3) & 15) * 128;
    const int mb  = bh & 1;

    const float L2E = 1.4426950408889634f;

    bf16x8 aq[4];
    {
        const float* qp = q + ((size_t)bh * cS + qb + wv * 32 + l31) * cD + h * 8;
#pragma unroll
        for (int dc = 0; dc < 4; ++dc)
            aq[dc] = pack8s(*(const f32x4*)(qp + dc * 16),
                            *(const f32x4*)(qp + dc * 16 + 4), 0.125f * L2E);
    }

    f32x16 acc[2] = {};
    float lsum = 0.f;

    const int sr0 = tid >> 4;
    const int c4  = (tid & 15) << 2;
    const int ka0 = sr0 * 64
        + ((((c4 >> 3) ^ (sr0 & 7) ^ (((sr0 >> 3) & 1) << 2)) << 3))
        + (c4 & 7);
    const float* kg = k + (size_t)bh * cS * cD;
    const float* vg = v + (size_t)bh * cS * cD;
    const float* mq = mask + (size_t)mb * cS * cS
                           + (size_t)(qb + wv * 32 + l31) * cS + h * 4;

    const int g0 = gkey(l31);
    const int g1 = gkey(32 + l31);
    const int vb0 = l31 * 64;
    const int vb1 = (32 + l31) * 64;

#pragma unroll
    for (int t = 0; t < 2; ++t)
#pragma unroll
        for (int j = 0; j < 4; ++j) {
            f32x4 kj = *(const f32x4*)(kg + t * 4096 + j * 1024 + tid * 4);
            f32x4 vj = *(const f32x4*)(vg + t * 4096 + j * 1024 + tid * 4);
            *(bf16x4*)&sK[t][ka0 + j * 1024] = pack4(kj);
#pragma unroll
            for (int i = 0; i < 4; ++i) {
                int d = c4 + i;
                sV[t][d * 64 + ((((j * 2) + (sr0 >> 3)) ^ gkey(d)) << 3) + (sr0 & 7)]
                    = bfbits(vj[i]);
            }
        }

    for (int pt = 0; pt < 16; ++pt) {
        const int base = pt * 2;
        const bool more = (pt + 1 < 16);
        const int nb = more ? base + 2 : base;

        f32x4 KPe[4], VPe[4], KPo[4], VPo[4];
#pragma unroll
        for (int j = 0; j < 4; ++j) {
            KPe[j] = *(const f32x4*)(kg + (size_t)nb * 4096 + j * 1024 + tid * 4);
            VPe[j] = *(const f32x4*)(vg + (size_t)nb * 4096 + j * 1024 + tid * 4);
            KPo[j] = *(const f32x4*)(kg + (size_t)(nb + 1) * 4096 + j * 1024 + tid * 4);
            VPo[j] = *(const f32x4*)(vg + (size_t)(nb + 1) * 4096 + j * 1024 + tid * 4);
        }

        __syncthreads();

#pragma unroll
        for (int t = 0; t < 2; ++t) {
            const unsigned short* sKt = sK[t];
            const unsigned short* sVt = sV[t];
#pragma unroll
            for (int gg = 0; gg < 2; ++gg) {
                const float* mrow = mq + (size_t)(base + t) * 64 + gg * 32;
                f32x4 mk[4];
#pragma unroll
                for (int j = 0; j < 4; ++j)
                    mk[j] = *(const f32x4*)(mrow + j * 8);

                const int rb = (gg * 32 + l31) * 64;
                bf16x8 kf[4];
#pragma unroll
                for (int dc = 0; dc < 4; ++dc)
                    kf[dc] = *(const bf16x8*)(&sKt[rb + (((dc * 2 + h) ^ swk) << 3)]);
                f32x16 s = {};
#pragma unroll
                for (int dc = 0; dc < 4; ++dc)
                    s = __builtin_amdgcn_mfma_f32_32x32x16_bf16(kf[dc], aq[dc], s, 0, 0, 0);

                float p[16];
#pragma unroll
                for (int r = 0; r < 16; ++r)
                    p[r] = __builtin_amdgcn_exp2f(fmaf(mk[r >> 2][r & 3], L2E, s[r]));
#pragma unroll
                for (int r = 0; r < 16; ++r)
                    lsum += p[r];

                unsigned int pk[8];
#pragma unroll
                for (int i = 0; i < 8; ++i)
                    pk[i] = (unsigned int)bfbits(p[2 * i])
                          | ((unsigned int)bfbits(p[2 * i + 1]) << 16);
                asm("v_permlane32_swap_b32 %0, %1" : "+v"(pk[0]), "+v"(pk[2]));
                asm("v_permlane32_swap_b32 %0, %1" : "+v"(pk[1]), "+v"(pk[3]));
                asm("v_permlane32_swap_b32 %0, %1" : "+v"(pk[4]), "+v"(pk[6]));
                asm("v_permlane32_swap_b32 %0, %1" : "+v"(pk[5]), "+v"(pk[7]));
                u32x4 ua = {pk[0], pk[1], pk[2], pk[3]};
                u32x4 ub = {pk[4], pk[5], pk[6], pk[7]};
                bf16x8 fA0 = __builtin_bit_cast(bf16x8, ua);
                bf16x8 fA1 = __builtin_bit_cast(bf16x8, ub);

#pragma unroll
                for (int kc = 0; kc < 2; ++kc) {
                    const int kb = gg * 4 + kc * 2 + h;
                    bf16x8 bv0 = *(const bf16x8*)(&sVt[vb0 + ((kb ^ g0) << 3)]);
                    bf16x8 bv1 = *(const bf16x8*)(&sVt[vb1 + ((kb ^ g1) << 3)]);
                    acc[0] = __builtin_amdgcn_mfma_f32_32x32x16_bf16(
                        kc ? fA1 : fA0, bv0, acc[0], 0, 0, 0);
                    acc[1] = __builtin_amdgcn_mfma_f32_32x32x16_bf16(
                        kc ? fA1 : fA0, bv1, acc[1], 0, 0, 0);
                }
            }
        }

        __syncthreads();

        if (more) {
#pragma unroll
            for (int j = 0; j < 4; ++j) {
                *(bf16x4*)&sK[0][ka0 + j * 1024] = pack4(KPe[j]);
                *(bf16x4*)&sK[1][ka0 + j * 1024] = pack4(KPo[j]);
#pragma unroll
                for (int i = 0; i < 4; ++i) {
                    int d = c4 + i;
                    int va = d * 64 + ((((j * 2) + (sr0 >> 3)) ^ gkey(d)) << 3) + (sr0 & 7);
                    sV[0][va] = bfbits(VPe[j][i]);
                    sV[1][va] = bfbits(VPo[j][i]);
                }
            }
        }
    }

    lsum += __shfl_xor(lsum, 32, 64);
#pragma unroll
    for (int r = 0; r < 16; ++r) {
        const int qrow = (r & 3) + 8 * (r >> 2) + 4 * h;
        const float rl = 1.0f / __shfl(lsum, qrow, 64);
        float* op = out + ((size_t)bh * cS + qb + wv * 32 + qrow) * cD + l31;
        op[0]  = acc[0][r] * rl;
        op[32] = acc[1][r] * rl;
    }
}

extern "C" void kernel_launch(void* const* d_in, const int* in_sizes, int n_in,
                              void* d_out, int out_size, void* d_ws, size_t ws_size,
                              hipStream_t stream) {
    const float* q = (const float*)d_in[0];
    const float* k = (const float*)d_in[1];
    const float* v = (const float*)d_in[2];
    const float* m = (const float*)d_in[3];
    float* o = (float*)d_out;

    // workspace: wsL [2][BH*S] floats, then wsO [BH*S*D] floats
    const size_t nL   = (size_t)2 * cBH * cS;                 // 131072 floats
    const size_t nO   = (size_t)cBH * cS * cD;                // 4194304 floats
    const size_t need = (nL + nO) * sizeof(float);            // ~16.5 MB

    if (d_ws != nullptr && ws_size >= need) {
        float* wsL = (float*)d_ws;
        float* wsO = wsL + nL;
        sdpa_part_kernel<8><<<dim3(512), 512, 0, stream>>>(q, k, v, m, o, wsO, wsL);
        sdpa_merge_kernel<<<dim3((unsigned)(nO / 8 / 256)), 256, 0, stream>>>(o, wsO, wsL);
    } else {
        sdpa_flash_kernel<<<dim3(512), 256, 0, stream>>>(q, k, v, m, o);
    }
}